// Round 9
// baseline (309.356 us; speedup 1.0000x reference)
//
#include <hip/hip_runtime.h>
#include <hip/hip_bf16.h>
#include <stdint.h>

#define B_      4
#define CIN     512
#define COUT    512
#define L_      4096
#define K_      7
#define OUT_LEN 4090

typedef unsigned short ushort_t;
typedef __attribute__((ext_vector_type(8))) __bf16 bf16x8;
typedef __attribute__((ext_vector_type(4))) float f32x4;

__device__ __forceinline__ uint32_t f2bf(float f) {
    uint32_t u = __float_as_uint(f);
    return (u + 0x7fffu + ((u >> 16) & 1u)) >> 16;
}

__device__ __forceinline__ uint32_t pack2bf(float s0, float s1) {   // s0 -> low 16
    __hip_bfloat162 h = __float22bfloat162_rn(make_float2(s0, s1));
    uint32_t r;
    __builtin_memcpy(&r, &h, 4);
    return r;
}

// interp one packed channel-pair: wl/wh = bf16x2 at u / u+1; returns bf16x2 sample
__device__ __forceinline__ uint32_t interp1(uint32_t wl, uint32_t wh, float g0, float g1) {
    const float l0 = __uint_as_float(wl << 16);
    const float l1 = __uint_as_float(wl & 0xffff0000u);
    const float h0 = __uint_as_float(wh << 16);
    const float h1 = __uint_as_float(wh & 0xffff0000u);
    return pack2bf(g0 * l0 + g1 * h0, g0 * l1 + g1 * h1);
}

// ---------------- kernel 1: weight reorder+cast (coalesced): Wr[k][d][c] bf16 ----------------
__global__ __launch_bounds__(256)
void reorder_w_kernel(const float* __restrict__ w, uint32_t* __restrict__ Wr) {
    const int d   = blockIdx.x;        // 512 blocks
    const int tid = threadIdx.x;       // = cpair 0..255
    __shared__ float wrow[3584];
    const float4* src = (const float4*)(w + (size_t)d * 3584);
    for (int e = tid; e < 896; e += 256) ((float4*)wrow)[e] = src[e];
    __syncthreads();
    #pragma unroll
    for (int k = 0; k < K_; ++k) {
        const float w0 = wrow[tid * 14 + k];        // c = 2*tid
        const float w1 = wrow[tid * 14 + 7 + k];    // c = 2*tid+1
        Wr[((size_t)(k * 512 + d) << 8) + tid] = (f2bf(w1) << 16) | f2bf(w0);
    }
}

// ---------------- kernel 2: fused interp + bf16 MFMA GEMM ----------------
// grid (32, 4, 4), 256 threads (4 waves). Wave wv owns o-quarter [wv*32, wv*32+32)
// x all 128 d  ->  each (o,k) sample interpolated exactly once. A frags are
// wave-identical global b128 loads (L1-served); k-loop is barrier-free.
__global__ __launch_bounds__(256, 2)
void fused_kernel(const float* __restrict__ x, const float* __restrict__ offs,
                  const ushort_t* __restrict__ Wr, const float* __restrict__ bias,
                  float* __restrict__ out) {
    const int o0   = blockIdx.x * 128;
    const int d0   = blockIdx.y * 128;
    const int b    = blockIdx.z;
    const int tid  = threadIdx.x;
    const int wv   = tid >> 6;
    const int lane = tid & 63;
    const int m16  = lane & 15;
    const int quad = lane >> 4;
    const int ob   = wv * 32;          // o-quarter base (block-local)

    // XTB[col][word]: packed bf16 channel-pair; cpair cp (cpg=cp>>1, h=cp&1)
    // stored at word ((cpg ^ (col & 7)) << 1) | h   (layout verified in R8)
    __shared__ __align__(16) uint32_t XTB[136 * 16];   // 8704 B
    __shared__ int    SU[896];                         // u0 - o0 per (k, ol)
    __shared__ float2 PG[896];                         // (g0, g1)

    // ---- interp params (once per block) ----
    for (int e = tid; e < 896; e += 256) {
        const int k  = e >> 7;
        const int ol = e & 127;
        int o = o0 + ol; if (o > OUT_LEN - 1) o = OUT_LEN - 1;
        const float t0  = (float)o;
        const float off = offs[((size_t)b * OUT_LEN + o) * K_ + k];
        float T = t0 + (float)k + off;
        T = fmaxf(T, t0);
        T = fminf(T, t0 + 6.0f);
        int u0 = (int)floorf(T);
        if (u0 > L_ - 2) u0 = L_ - 2;
        const float g0 = fmaxf(1.0f - fabsf((float)u0 - T), 0.0f);
        const float g1 = fmaxf(1.0f - fabsf((float)(u0 + 1) - T), 0.0f);
        SU[e] = u0 - o0;
        PG[e] = make_float2(g0, g1);
    }

    f32x4 acc[8][2];
    #pragma unroll
    for (int i = 0; i < 8; ++i) {
        #pragma unroll
        for (int j = 0; j < 2; ++j) acc[i][j] = (f32x4){0.f, 0.f, 0.f, 0.f};
    }

    const float* xb = x + (size_t)b * CIN * L_ + o0;
    const int q2 = quad * 2;

    for (int cc = 0; cc < 16; ++cc) {
        __syncthreads();   // previous cc's XTB readers done (cc=0: params fence)

        // ---- stage XTB: 16 cpairs x 136 cols, bf16-packed + swizzled ----
        {
            const float* xc = xb + (size_t)cc * 32 * L_;
            #pragma unroll
            for (int r = 0; r < 3; ++r) {
                const int e = r * 256 + tid;
                if (e < 544) {                       // 16 cpairs * 34 float4
                    const int cp   = e / 34;
                    const int col4 = e - cp * 34;
                    const int colb = col4 * 4;
                    const float* p0 = xc + (size_t)(2 * cp) * L_ + colb;
                    const float* p1 = p0 + L_;
                    float4 v0, v1;
                    if (o0 + colb + 3 < L_) {
                        v0 = *(const float4*)p0;
                        v1 = *(const float4*)p1;
                    } else {
                        float a0 = (o0 + colb + 0 < L_) ? p0[0] : 0.f;
                        float a1 = (o0 + colb + 1 < L_) ? p0[1] : 0.f;
                        float a2 = (o0 + colb + 2 < L_) ? p0[2] : 0.f;
                        float a3 = (o0 + colb + 3 < L_) ? p0[3] : 0.f;
                        float b0 = (o0 + colb + 0 < L_) ? p1[0] : 0.f;
                        float b1 = (o0 + colb + 1 < L_) ? p1[1] : 0.f;
                        float b2 = (o0 + colb + 2 < L_) ? p1[2] : 0.f;
                        float b3 = (o0 + colb + 3 < L_) ? p1[3] : 0.f;
                        v0 = make_float4(a0, a1, a2, a3);
                        v1 = make_float4(b0, b1, b2, b3);
                    }
                    const float* f0 = (const float*)&v0;
                    const float* f1 = (const float*)&v1;
                    const int cpg = cp >> 1, h = cp & 1;
                    #pragma unroll
                    for (int ii = 0; ii < 4; ++ii) {
                        const int col = colb + ii;
                        XTB[col * 16 + (((cpg ^ (col & 7)) << 1) | h)] =
                            pack2bf(f0[ii], f1[ii]);
                    }
                }
            }
        }
        __syncthreads();   // XTB(cc) visible; no barriers for the next 7 steps

        #pragma unroll
        for (int k = 0; k < K_; ++k) {
            // ---- A fragments: 8 wave-identical global b128 loads (L1-served) ----
            const ushort_t* Ak = Wr + ((size_t)(k * 512 + d0 + m16)) * 512
                                    + cc * 32 + quad * 8;
            bf16x8 af[8];
            #pragma unroll
            for (int i = 0; i < 8; ++i)
                af[i] = *(const bf16x8*)(Ak + (size_t)i * 16 * 512);

            // ---- B fragments: 2 per wave, each sample interpolated once ----
            bf16x8 bfr[2];
            #pragma unroll
            for (int j = 0; j < 2; ++j) {
                const int row = (k << 7) | (ob + j * 16 + m16);
                const int u   = SU[row];
                const float2 g = PG[row];
                const uint32_t* Xr0 = &XTB[u * 16];
                const uint32_t* Xr1 = Xr0 + 16;
                const int s0 = u & 7, s1 = (u + 1) & 7;
                const uint2 a0 = *(const uint2*)&Xr0[((q2     ^ s0) << 1)];
                const uint2 a1 = *(const uint2*)&Xr0[(((q2+1) ^ s0) << 1)];
                const uint2 c0 = *(const uint2*)&Xr1[((q2     ^ s1) << 1)];
                const uint2 c1 = *(const uint2*)&Xr1[(((q2+1) ^ s1) << 1)];
                uint4 rr;
                rr.x = interp1(a0.x, c0.x, g.x, g.y);   // c = quad*8+0,1
                rr.y = interp1(a0.y, c0.y, g.x, g.y);   // c = quad*8+2,3
                rr.z = interp1(a1.x, c1.x, g.x, g.y);   // c = quad*8+4,5
                rr.w = interp1(a1.y, c1.y, g.x, g.y);   // c = quad*8+6,7
                __builtin_memcpy(&bfr[j], &rr, 16);
            }

            #pragma unroll
            for (int i = 0; i < 8; ++i) {
                #pragma unroll
                for (int j = 0; j < 2; ++j)
                    acc[i][j] = __builtin_amdgcn_mfma_f32_16x16x32_bf16(af[i], bfr[j], acc[i][j], 0, 0, 0);
            }
        }
    }

    // ---- epilogue (verified C/D layout: col=o (m16), row=quad*4+r) ----
    #pragma unroll
    for (int i = 0; i < 8; ++i) {
        const int dd = d0 + i * 16 + quad * 4;
        float bv[4];
        #pragma unroll
        for (int r = 0; r < 4; ++r) bv[r] = bias[dd + r];
        #pragma unroll
        for (int j = 0; j < 2; ++j) {
            const int oo = o0 + ob + j * 16 + m16;
            if (oo < OUT_LEN) {
                float* op = out + (size_t)b * COUT * OUT_LEN + (size_t)dd * OUT_LEN + oo;
                #pragma unroll
                for (int r = 0; r < 4; ++r)
                    op[(size_t)r * OUT_LEN] = acc[i][j][r] + bv[r];
            }
        }
    }
}

// ---------------- fallback (round-1 fp32 kernel, used only if ws too small) ----------------
#define BM 64
#define BN 64
#define BC 8
#define TT (BC * K_)

__global__ __launch_bounds__(256, 2)
void deform_conv1d_fallback(const float* __restrict__ x, const float* __restrict__ offsets,
                            const float* __restrict__ weight, const float* __restrict__ bias,
                            float* __restrict__ out) {
    const int o0 = blockIdx.x * BN, d0 = blockIdx.y * BM, b = blockIdx.z, tid = threadIdx.x;
    __shared__ int   SU[BN * K_];
    __shared__ float SG0[BN * K_], SG1[BN * K_];
    __shared__ float XT[BC][BN + 8];
    __shared__ float S[BC][K_][BN];
    __shared__ float WT[BM][TT + 1];
    for (int e = tid; e < BN * K_; e += 256) {
        const int ol = e / K_, k = e % K_, o = o0 + ol;
        int u0rel = 0; float g0 = 0.f, g1 = 0.f;
        if (o < OUT_LEN) {
            const float t0 = (float)o;
            const float off = offsets[(size_t)b * OUT_LEN * K_ + (size_t)o * K_ + k];
            float T = fminf(fmaxf(t0 + (float)k + off, t0), t0 + 6.0f);
            int u0 = (int)floorf(T); if (u0 > L_ - 2) u0 = L_ - 2;
            g0 = fmaxf(1.0f - fabsf((float)u0 - T), 0.0f);
            g1 = fmaxf(1.0f - fabsf((float)(u0 + 1) - T), 0.0f);
            u0rel = u0 - o0;
        }
        SU[e] = u0rel; SG0[e] = g0; SG1[e] = g1;
    }
    float acc[4][4];
    #pragma unroll
    for (int i = 0; i < 4; ++i) {
        #pragma unroll
        for (int j = 0; j < 4; ++j) acc[i][j] = 0.f;
    }
    const int ty = tid >> 4, tx = tid & 15;
    const float* xb = x + (size_t)b * CIN * L_;
    for (int c0 = 0; c0 < CIN; c0 += BC) {
        __syncthreads();
        for (int e = tid; e < BC * (BN + 7); e += 256) {
            const int cl = e / (BN + 7), j = e % (BN + 7), pos = o0 + j;
            XT[cl][j] = (pos < L_) ? xb[(size_t)(c0 + cl) * L_ + pos] : 0.f;
        }
        for (int e = tid; e < BM * TT; e += 256) {
            const int d = e / TT, t = e % TT;
            WT[d][t] = weight[(size_t)(d0 + d) * (CIN * K_) + c0 * K_ + t];
        }
        __syncthreads();
        for (int e = tid; e < BC * K_ * BN; e += 256) {
            const int cl = e / (K_ * BN), r = e % (K_ * BN), k = r / BN, ol = r % BN;
            const int p = ol * K_ + k, u = SU[p];
            S[cl][k][ol] = SG0[p] * XT[cl][u] + SG1[p] * XT[cl][u + 1];
        }
        __syncthreads();
        #pragma unroll
        for (int t = 0; t < TT; ++t) {
            const int cl = t / K_, k = t % K_;
            const float4 s4 = *(const float4*)&S[cl][k][tx * 4];
            const float w0 = WT[ty * 4 + 0][t], w1 = WT[ty * 4 + 1][t];
            const float w2 = WT[ty * 4 + 2][t], w3 = WT[ty * 4 + 3][t];
            acc[0][0] += w0 * s4.x; acc[0][1] += w0 * s4.y; acc[0][2] += w0 * s4.z; acc[0][3] += w0 * s4.w;
            acc[1][0] += w1 * s4.x; acc[1][1] += w1 * s4.y; acc[1][2] += w1 * s4.z; acc[1][3] += w1 * s4.w;
            acc[2][0] += w2 * s4.x; acc[2][1] += w2 * s4.y; acc[2][2] += w2 * s4.z; acc[2][3] += w2 * s4.w;
            acc[3][0] += w3 * s4.x; acc[3][1] += w3 * s4.y; acc[3][2] += w3 * s4.z; acc[3][3] += w3 * s4.w;
        }
    }
    #pragma unroll
    for (int i = 0; i < 4; ++i) {
        const int d = d0 + ty * 4 + i;
        const float bvv = bias[d];
        #pragma unroll
        for (int j = 0; j < 4; ++j) {
            const int o = o0 + tx * 4 + j;
            if (o < OUT_LEN)
                out[(size_t)b * COUT * OUT_LEN + (size_t)d * OUT_LEN + o] = acc[i][j] + bvv;
        }
    }
}

extern "C" void kernel_launch(void* const* d_in, const int* in_sizes, int n_in,
                              void* d_out, int out_size, void* d_ws, size_t ws_size,
                              hipStream_t stream) {
    const float* x       = (const float*)d_in[0];
    const float* offsets = (const float*)d_in[1];
    const float* weight  = (const float*)d_in[2];
    const float* bias    = (const float*)d_in[3];
    float* out = (float*)d_out;

    const size_t WR_BYTES = (size_t)512 * 512 * 7 * 2;

    if (ws_size < WR_BYTES) {
        dim3 grid((OUT_LEN + BN - 1) / BN, COUT / BM, B_);
        deform_conv1d_fallback<<<grid, 256, 0, stream>>>(x, offsets, weight, bias, out);
        return;
    }

    uint32_t* Wr_u32 = (uint32_t*)d_ws;
    ushort_t* Wr     = (ushort_t*)d_ws;

    reorder_w_kernel<<<512, 256, 0, stream>>>(weight, Wr_u32);
    fused_kernel<<<dim3(32, 4, B_), 256, 0, stream>>>(x, offsets, Wr, bias, out);
}

// Round 10
// 187.823 us; speedup vs baseline: 1.6471x; 1.6471x over previous
//
#include <hip/hip_runtime.h>
#include <hip/hip_bf16.h>
#include <stdint.h>

#define B_      4
#define CIN     512
#define COUT    512
#define L_      4096
#define K_      7
#define OUT_LEN 4090

typedef unsigned short ushort_t;
typedef __attribute__((ext_vector_type(8))) __bf16 bf16x8;
typedef __attribute__((ext_vector_type(4))) float f32x4;

__device__ __forceinline__ uint32_t f2bf(float f) {
    uint32_t u = __float_as_uint(f);
    return (u + 0x7fffu + ((u >> 16) & 1u)) >> 16;
}

__device__ __forceinline__ uint32_t pack2bf(float s0, float s1) {   // s0 -> low 16
    __hip_bfloat162 h = __float22bfloat162_rn(make_float2(s0, s1));
    uint32_t r;
    __builtin_memcpy(&r, &h, 4);
    return r;
}

// interp one packed channel-pair: wl/wh = bf16x2 at u / u+1; returns bf16x2 sample
__device__ __forceinline__ uint32_t interp1(uint32_t wl, uint32_t wh, float g0, float g1) {
    const float l0 = __uint_as_float(wl << 16);
    const float l1 = __uint_as_float(wl & 0xffff0000u);
    const float h0 = __uint_as_float(wh << 16);
    const float h1 = __uint_as_float(wh & 0xffff0000u);
    return pack2bf(g0 * l0 + g1 * h0, g0 * l1 + g1 * h1);
}

__device__ __forceinline__ void async16(const void* g, void* l) {
    __builtin_amdgcn_global_load_lds(
        (const __attribute__((address_space(1))) unsigned int*)g,
        (__attribute__((address_space(3))) unsigned int*)l, 16, 0, 0);
}

// ------- kernel 1: weight reorder+cast: Wr2[k][cc][d][c32] bf16 (staging-contiguous) -------
__global__ __launch_bounds__(256)
void reorder_w_kernel(const float* __restrict__ w, uint32_t* __restrict__ Wr) {
    const int d   = blockIdx.x;        // 512 blocks
    const int tid = threadIdx.x;       // cpair: c = 2*tid
    __shared__ float wrow[3584];
    const float4* src = (const float4*)(w + (size_t)d * 3584);
    for (int e = tid; e < 896; e += 256) ((float4*)wrow)[e] = src[e];
    __syncthreads();
    const int cc  = tid >> 4;          // c-chunk (c>>5)
    const int clp = tid & 15;          // pair index within chunk
    #pragma unroll
    for (int k = 0; k < K_; ++k) {
        const float w0 = wrow[tid * 14 + k];        // c = 2*tid
        const float w1 = wrow[tid * 14 + 7 + k];    // c = 2*tid+1
        Wr[((size_t)((k * 16 + cc) * 512 + d)) * 16 + clp] = (f2bf(w1) << 16) | f2bf(w0);
    }
}

// ---------------- kernel 2: fused interp + bf16 MFMA GEMM ----------------
// grid (32, 4, 4), 256 threads (4 waves). Wave wv owns o-quarter [wv*32, +32)
// x all 128 d (interp once per sample). A staged to LDS per-cc in k-batches
// via global_load_lds; k-steps between barriers are rendezvous-free.
__global__ __launch_bounds__(256, 2)
void fused_kernel(const float* __restrict__ x, const float* __restrict__ offs,
                  const ushort_t* __restrict__ Wr, const float* __restrict__ bias,
                  float* __restrict__ out) {
    const int o0   = blockIdx.x * 128;
    const int d0   = blockIdx.y * 128;
    const int b    = blockIdx.z;
    const int tid  = threadIdx.x;
    const int wv   = tid >> 6;
    const int lane = tid & 63;
    const int m16  = lane & 15;
    const int quad = lane >> 4;
    const int ob   = wv * 32;          // o-quarter base (block-local)

    __shared__ __align__(16) ushort_t As[4 * 128 * 32];   // A slots (k&3): 32768 B
    __shared__ __align__(16) uint32_t XTB[136 * 16];      // swizzled bf16 x-slab: 8704 B
    __shared__ int    SU[896];
    __shared__ float2 PG[896];

    // ---- interp params (once per block) ----
    for (int e = tid; e < 896; e += 256) {
        const int k  = e >> 7;
        const int ol = e & 127;
        int o = o0 + ol; if (o > OUT_LEN - 1) o = OUT_LEN - 1;
        const float t0  = (float)o;
        const float off = offs[((size_t)b * OUT_LEN + o) * K_ + k];
        float T = t0 + (float)k + off;
        T = fmaxf(T, t0);
        T = fminf(T, t0 + 6.0f);
        int u0 = (int)floorf(T);
        if (u0 > L_ - 2) u0 = L_ - 2;
        const float g0 = fmaxf(1.0f - fabsf((float)u0 - T), 0.0f);
        const float g1 = fmaxf(1.0f - fabsf((float)(u0 + 1) - T), 0.0f);
        SU[e] = u0 - o0;
        PG[e] = make_float2(g0, g1);
    }

    f32x4 acc[8][2];
    #pragma unroll
    for (int i = 0; i < 8; ++i) {
        #pragma unroll
        for (int j = 0; j < 2; ++j) acc[i][j] = (f32x4){0.f, 0.f, 0.f, 0.f};
    }

    const float* xb = x + (size_t)b * CIN * L_ + o0;
    const int q2 = quad * 2;

// stage NISS*256 16B-chunks of Wr2 for k batch starting K0 into As slots (k&3)
#define ISSUE_DMA_A(CC, K0, NISS)                                                 \
    {                                                                             \
        _Pragma("unroll")                                                         \
        for (int n_ = 0; n_ < (NISS); ++n_) {                                     \
            const int ew_ = n_ * 256 + wv * 64;       /* wave-base e (64-aligned) */ \
            const int kk_ = (K0) + (ew_ >> 9);                                    \
            const int rb_ = ew_ & 511;                                            \
            const int e_  = n_ * 256 + tid;                                       \
            const int r_  = e_ & 511;                                             \
            const ushort_t* g_ = Wr                                                \
                + ((size_t)((kk_ * 16 + (CC)) * 512 + d0 + (r_ >> 2))) * 32       \
                + (r_ & 3) * 8;                                                   \
            async16(g_, (void*)(As + (size_t)(kk_ & 3) * 4096 + (size_t)rb_ * 8)); \
        }                                                                         \
    }

#define STAGE_XTB(CC)                                                             \
    {                                                                             \
        const float* xc = xb + (size_t)(CC) * 32 * L_;                            \
        _Pragma("unroll")                                                         \
        for (int r = 0; r < 3; ++r) {                                             \
            const int e = r * 256 + tid;                                          \
            if (e < 544) {                                                        \
                const int cp   = e / 34;                                          \
                const int col4 = e - cp * 34;                                     \
                const int colb = col4 * 4;                                        \
                const float* p0 = xc + (size_t)(2 * cp) * L_ + colb;              \
                const float* p1 = p0 + L_;                                        \
                float4 v0, v1;                                                    \
                if (o0 + colb + 3 < L_) {                                         \
                    v0 = *(const float4*)p0;                                      \
                    v1 = *(const float4*)p1;                                      \
                } else {                                                          \
                    float a0 = (o0 + colb + 0 < L_) ? p0[0] : 0.f;                \
                    float a1 = (o0 + colb + 1 < L_) ? p0[1] : 0.f;                \
                    float a2 = (o0 + colb + 2 < L_) ? p0[2] : 0.f;                \
                    float a3 = (o0 + colb + 3 < L_) ? p0[3] : 0.f;                \
                    float b0 = (o0 + colb + 0 < L_) ? p1[0] : 0.f;                \
                    float b1 = (o0 + colb + 1 < L_) ? p1[1] : 0.f;                \
                    float b2 = (o0 + colb + 2 < L_) ? p1[2] : 0.f;                \
                    float b3 = (o0 + colb + 3 < L_) ? p1[3] : 0.f;                \
                    v0 = make_float4(a0, a1, a2, a3);                             \
                    v1 = make_float4(b0, b1, b2, b3);                             \
                }                                                                 \
                const float* f0 = (const float*)&v0;                              \
                const float* f1 = (const float*)&v1;                              \
                const int cpg = cp >> 1, h = cp & 1;                              \
                _Pragma("unroll")                                                 \
                for (int ii = 0; ii < 4; ++ii) {                                  \
                    const int col = colb + ii;                                    \
                    XTB[col * 16 + (((cpg ^ (col & 7)) << 1) | h)] =              \
                        pack2bf(f0[ii], f1[ii]);                                  \
                }                                                                 \
            }                                                                     \
        }                                                                         \
    }

#define STEP(K)                                                                   \
    {                                                                             \
        const ushort_t* Ab_ = As + (size_t)((K) & 3) * 4096;                      \
        bf16x8 af_[8];                                                            \
        _Pragma("unroll")                                                         \
        for (int i_ = 0; i_ < 8; ++i_)                                            \
            af_[i_] = *(const bf16x8*)&Ab_[(i_ * 16 + m16) * 32 + quad * 8];      \
        bf16x8 bfr_[2];                                                           \
        _Pragma("unroll")                                                         \
        for (int j_ = 0; j_ < 2; ++j_) {                                          \
            const int row_ = ((K) << 7) | (ob + j_ * 16 + m16);                   \
            const int u_ = SU[row_];                                              \
            const float2 g_ = PG[row_];                                           \
            const uint32_t* Xr0_ = &XTB[u_ * 16];                                 \
            const uint32_t* Xr1_ = Xr0_ + 16;                                     \
            const int s0_ = u_ & 7, s1_ = (u_ + 1) & 7;                           \
            const uint2 a0_ = *(const uint2*)&Xr0_[((q2     ^ s0_) << 1)];        \
            const uint2 a1_ = *(const uint2*)&Xr0_[(((q2+1) ^ s0_) << 1)];        \
            const uint2 c0_ = *(const uint2*)&Xr1_[((q2     ^ s1_) << 1)];        \
            const uint2 c1_ = *(const uint2*)&Xr1_[(((q2+1) ^ s1_) << 1)];        \
            uint4 rr_;                                                            \
            rr_.x = interp1(a0_.x, c0_.x, g_.x, g_.y);                            \
            rr_.y = interp1(a0_.y, c0_.y, g_.x, g_.y);                            \
            rr_.z = interp1(a1_.x, c1_.x, g_.x, g_.y);                            \
            rr_.w = interp1(a1_.y, c1_.y, g_.x, g_.y);                            \
            __builtin_memcpy(&bfr_[j_], &rr_, 16);                                \
        }                                                                         \
        _Pragma("unroll")                                                         \
        for (int i_ = 0; i_ < 8; ++i_) {                                          \
            _Pragma("unroll")                                                     \
            for (int j_ = 0; j_ < 2; ++j_)                                        \
                acc[i_][j_] = __builtin_amdgcn_mfma_f32_16x16x32_bf16(af_[i_], bfr_[j_], acc[i_][j_], 0, 0, 0); \
        }                                                                         \
    }

    for (int cc = 0; cc < 16; ++cc) {
        __syncthreads();               // prev cc's As/XTB readers done (cc=0: params fence)
        ISSUE_DMA_A(cc, 0, 8);         // k=0..3 -> slots 0..3 (latency hides behind XTB stage)
        STAGE_XTB(cc);
        __syncthreads();               // drains vmcnt: As[0..3] + XTB ready
        STEP(0); STEP(1); STEP(2);
        __syncthreads();               // slots 0..2 readers done
        ISSUE_DMA_A(cc, 4, 6);         // k=4..6 -> slots 0..2 (latency hides behind STEP(3))
        STEP(3);
        __syncthreads();               // drains vmcnt: As[4..6] ready
        STEP(4); STEP(5); STEP(6);
    }

    // ---- epilogue (verified C/D layout: col=o (m16), row=quad*4+r) ----
    #pragma unroll
    for (int i = 0; i < 8; ++i) {
        const int dd = d0 + i * 16 + quad * 4;
        float bv[4];
        #pragma unroll
        for (int r = 0; r < 4; ++r) bv[r] = bias[dd + r];
        #pragma unroll
        for (int j = 0; j < 2; ++j) {
            const int oo = o0 + ob + j * 16 + m16;
            if (oo < OUT_LEN) {
                float* op = out + (size_t)b * COUT * OUT_LEN + (size_t)dd * OUT_LEN + oo;
                #pragma unroll
                for (int r = 0; r < 4; ++r)
                    op[(size_t)r * OUT_LEN] = acc[i][j][r] + bv[r];
            }
        }
    }
#undef ISSUE_DMA_A
#undef STAGE_XTB
#undef STEP
}

// ---------------- fallback (round-1 fp32 kernel, used only if ws too small) ----------------
#define BM 64
#define BN 64
#define BC 8
#define TT (BC * K_)

__global__ __launch_bounds__(256, 2)
void deform_conv1d_fallback(const float* __restrict__ x, const float* __restrict__ offsets,
                            const float* __restrict__ weight, const float* __restrict__ bias,
                            float* __restrict__ out) {
    const int o0 = blockIdx.x * BN, d0 = blockIdx.y * BM, b = blockIdx.z, tid = threadIdx.x;
    __shared__ int   SU[BN * K_];
    __shared__ float SG0[BN * K_], SG1[BN * K_];
    __shared__ float XT[BC][BN + 8];
    __shared__ float S[BC][K_][BN];
    __shared__ float WT[BM][TT + 1];
    for (int e = tid; e < BN * K_; e += 256) {
        const int ol = e / K_, k = e % K_, o = o0 + ol;
        int u0rel = 0; float g0 = 0.f, g1 = 0.f;
        if (o < OUT_LEN) {
            const float t0 = (float)o;
            const float off = offsets[(size_t)b * OUT_LEN * K_ + (size_t)o * K_ + k];
            float T = fminf(fmaxf(t0 + (float)k + off, t0), t0 + 6.0f);
            int u0 = (int)floorf(T); if (u0 > L_ - 2) u0 = L_ - 2;
            g0 = fmaxf(1.0f - fabsf((float)u0 - T), 0.0f);
            g1 = fmaxf(1.0f - fabsf((float)(u0 + 1) - T), 0.0f);
            u0rel = u0 - o0;
        }
        SU[e] = u0rel; SG0[e] = g0; SG1[e] = g1;
    }
    float acc[4][4];
    #pragma unroll
    for (int i = 0; i < 4; ++i) {
        #pragma unroll
        for (int j = 0; j < 4; ++j) acc[i][j] = 0.f;
    }
    const int ty = tid >> 4, tx = tid & 15;
    const float* xb = x + (size_t)b * CIN * L_;
    for (int c0 = 0; c0 < CIN; c0 += BC) {
        __syncthreads();
        for (int e = tid; e < BC * (BN + 7); e += 256) {
            const int cl = e / (BN + 7), j = e % (BN + 7), pos = o0 + j;
            XT[cl][j] = (pos < L_) ? xb[(size_t)(c0 + cl) * L_ + pos] : 0.f;
        }
        for (int e = tid; e < BM * TT; e += 256) {
            const int d = e / TT, t = e % TT;
            WT[d][t] = weight[(size_t)(d0 + d) * (CIN * K_) + c0 * K_ + t];
        }
        __syncthreads();
        for (int e = tid; e < BC * K_ * BN; e += 256) {
            const int cl = e / (K_ * BN), r = e % (K_ * BN), k = r / BN, ol = r % BN;
            const int p = ol * K_ + k, u = SU[p];
            S[cl][k][ol] = SG0[p] * XT[cl][u] + SG1[p] * XT[cl][u + 1];
        }
        __syncthreads();
        #pragma unroll
        for (int t = 0; t < TT; ++t) {
            const int cl = t / K_, k = t % K_;
            const float4 s4 = *(const float4*)&S[cl][k][tx * 4];
            const float w0 = WT[ty * 4 + 0][t], w1 = WT[ty * 4 + 1][t];
            const float w2 = WT[ty * 4 + 2][t], w3 = WT[ty * 4 + 3][t];
            acc[0][0] += w0 * s4.x; acc[0][1] += w0 * s4.y; acc[0][2] += w0 * s4.z; acc[0][3] += w0 * s4.w;
            acc[1][0] += w1 * s4.x; acc[1][1] += w1 * s4.y; acc[1][2] += w1 * s4.z; acc[1][3] += w1 * s4.w;
            acc[2][0] += w2 * s4.x; acc[2][1] += w2 * s4.y; acc[2][2] += w2 * s4.z; acc[2][3] += w2 * s4.w;
            acc[3][0] += w3 * s4.x; acc[3][1] += w3 * s4.y; acc[3][2] += w3 * s4.z; acc[3][3] += w3 * s4.w;
        }
    }
    #pragma unroll
    for (int i = 0; i < 4; ++i) {
        const int d = d0 + ty * 4 + i;
        const float bvv = bias[d];
        #pragma unroll
        for (int j = 0; j < 4; ++j) {
            const int o = o0 + tx * 4 + j;
            if (o < OUT_LEN)
                out[(size_t)b * COUT * OUT_LEN + (size_t)d * OUT_LEN + o] = acc[i][j] + bvv;
        }
    }
}

extern "C" void kernel_launch(void* const* d_in, const int* in_sizes, int n_in,
                              void* d_out, int out_size, void* d_ws, size_t ws_size,
                              hipStream_t stream) {
    const float* x       = (const float*)d_in[0];
    const float* offsets = (const float*)d_in[1];
    const float* weight  = (const float*)d_in[2];
    const float* bias    = (const float*)d_in[3];
    float* out = (float*)d_out;

    const size_t WR_BYTES = (size_t)512 * 512 * 7 * 2;

    if (ws_size < WR_BYTES) {
        dim3 grid((OUT_LEN + BN - 1) / BN, COUT / BM, B_);
        deform_conv1d_fallback<<<grid, 256, 0, stream>>>(x, offsets, weight, bias, out);
        return;
    }

    uint32_t* Wr_u32 = (uint32_t*)d_ws;
    ushort_t* Wr     = (ushort_t*)d_ws;

    reorder_w_kernel<<<512, 256, 0, stream>>>(weight, Wr_u32);
    fused_kernel<<<dim3(32, 4, B_), 256, 0, stream>>>(x, offsets, Wr, bias, out);
}

// Round 11
// 185.447 us; speedup vs baseline: 1.6682x; 1.0128x over previous
//
#include <hip/hip_runtime.h>
#include <hip/hip_bf16.h>
#include <stdint.h>

#define B_      4
#define CIN     512
#define COUT    512
#define L_      4096
#define K_      7
#define OUT_LEN 4090

typedef unsigned short ushort_t;
typedef __attribute__((ext_vector_type(8))) __bf16 bf16x8;
typedef __attribute__((ext_vector_type(4))) float f32x4;

__device__ __forceinline__ uint32_t f2bf(float f) {
    uint32_t u = __float_as_uint(f);
    return (u + 0x7fffu + ((u >> 16) & 1u)) >> 16;
}

__device__ __forceinline__ uint32_t pack2bf(float s0, float s1) {   // s0 -> low 16
    __hip_bfloat162 h = __float22bfloat162_rn(make_float2(s0, s1));
    uint32_t r;
    __builtin_memcpy(&r, &h, 4);
    return r;
}

__device__ __forceinline__ uint32_t interp1(uint32_t wl, uint32_t wh, float g0, float g1) {
    const float l0 = __uint_as_float(wl << 16);
    const float l1 = __uint_as_float(wl & 0xffff0000u);
    const float h0 = __uint_as_float(wh << 16);
    const float h1 = __uint_as_float(wh & 0xffff0000u);
    return pack2bf(g0 * l0 + g1 * h0, g0 * l1 + g1 * h1);
}

__device__ __forceinline__ void async16(const void* g, void* l) {
    __builtin_amdgcn_global_load_lds(
        (const __attribute__((address_space(1))) unsigned int*)g,
        (__attribute__((address_space(3))) unsigned int*)l, 16, 0, 0);
}

// ------- kernel 1: weight reorder+cast: Wr2[k][cc][d][c32] bf16 (staging-contiguous) -------
__global__ __launch_bounds__(256)
void reorder_w_kernel(const float* __restrict__ w, uint32_t* __restrict__ Wr) {
    const int d   = blockIdx.x;
    const int tid = threadIdx.x;
    __shared__ float wrow[3584];
    const float4* src = (const float4*)(w + (size_t)d * 3584);
    for (int e = tid; e < 896; e += 256) ((float4*)wrow)[e] = src[e];
    __syncthreads();
    const int cc  = tid >> 4;
    const int clp = tid & 15;
    #pragma unroll
    for (int k = 0; k < K_; ++k) {
        const float w0 = wrow[tid * 14 + k];
        const float w1 = wrow[tid * 14 + 7 + k];
        Wr[((size_t)((k * 16 + cc) * 512 + d)) * 16 + clp] = (f2bf(w1) << 16) | f2bf(w0);
    }
}

// ------- kernel 2: prepack x into swizzled bf16 slabs: xpack[(b,cc,ob)][544 chunks] -------
__global__ __launch_bounds__(256)
void prepack_kernel(const float* __restrict__ x, uint32_t* __restrict__ xpack) {
    const int obx = blockIdx.x;   // 0..31
    const int cc  = blockIdx.y;   // 0..15
    const int b   = blockIdx.z;
    const int tid = threadIdx.x;
    const int o0  = obx * 128;
    __shared__ __align__(16) uint32_t XT[2176];
    const float* xc = x + ((size_t)b * CIN + cc * 32) * L_ + o0;
    #pragma unroll
    for (int r = 0; r < 3; ++r) {
        const int e = r * 256 + tid;
        if (e < 544) {
            const int cp   = e / 34;
            const int col4 = e - cp * 34;
            const int colb = col4 * 4;
            const float* p0 = xc + (size_t)(2 * cp) * L_ + colb;
            const float* p1 = p0 + L_;
            float4 v0, v1;
            if (o0 + colb + 3 < L_) {
                v0 = *(const float4*)p0;
                v1 = *(const float4*)p1;
            } else {
                float a0 = (o0 + colb + 0 < L_) ? p0[0] : 0.f;
                float a1 = (o0 + colb + 1 < L_) ? p0[1] : 0.f;
                float a2 = (o0 + colb + 2 < L_) ? p0[2] : 0.f;
                float a3 = (o0 + colb + 3 < L_) ? p0[3] : 0.f;
                float b0 = (o0 + colb + 0 < L_) ? p1[0] : 0.f;
                float b1 = (o0 + colb + 1 < L_) ? p1[1] : 0.f;
                float b2 = (o0 + colb + 2 < L_) ? p1[2] : 0.f;
                float b3 = (o0 + colb + 3 < L_) ? p1[3] : 0.f;
                v0 = make_float4(a0, a1, a2, a3);
                v1 = make_float4(b0, b1, b2, b3);
            }
            const float* f0 = (const float*)&v0;
            const float* f1 = (const float*)&v1;
            const int cpg = cp >> 1, h = cp & 1;
            #pragma unroll
            for (int ii = 0; ii < 4; ++ii) {
                const int col = colb + ii;
                XT[col * 16 + (((cpg ^ (col & 7)) << 1) | h)] = pack2bf(f0[ii], f1[ii]);
            }
        }
    }
    __syncthreads();
    uint4* dst = (uint4*)xpack + (size_t)((b * 16 + cc) * 32 + obx) * 544;
    const uint4* s4 = (const uint4*)XT;
    #pragma unroll
    for (int r = 0; r < 3; ++r) {
        const int e = r * 256 + tid;
        if (e < 544) dst[e] = s4[e];
    }
}

// ---------------- kernel 3: fused MFMA GEMM, all-DMA staging, static pipeline ----------------
__global__ __launch_bounds__(256, 2)
void fused_kernel(const float* __restrict__ offs, const ushort_t* __restrict__ Wr,
                  const uint32_t* __restrict__ xpack, const float* __restrict__ bias,
                  float* __restrict__ out) {
    const int bxi  = blockIdx.x;
    const int o0   = bxi * 128;
    const int d0   = blockIdx.y * 128;
    const int b    = blockIdx.z;
    const int tid  = threadIdx.x;
    const int wv   = tid >> 6;
    const int lane = tid & 63;
    const int m16  = lane & 15;
    const int quad = lane >> 4;
    const int ob   = wv * 32;
    const int q2   = quad * 2;

    // distinct symbols -> compiler-provable no-alias between DMA writes and ds_reads
    __shared__ __align__(16) ushort_t As0[4096], As1[4096], As2[4096], As3[4096]; // 4x8KB
    __shared__ __align__(16) uint32_t XTB0[2304], XTB1[2304];                     // 2x9216B (incl pad)
    __shared__ int    SU[896];
    __shared__ float2 PG[896];

#define ISSUE_A(KK, CC, ASP)                                                      \
    {                                                                             \
        _Pragma("unroll")                                                         \
        for (int r_ = 0; r_ < 2; ++r_) {                                          \
            const int c_ = r_ * 256 + tid;                                        \
            const int row_ = c_ >> 2, pc_ = c_ & 3;                               \
            const ushort_t* g_ = Wr                                               \
                + ((size_t)(((KK) * 16 + (CC)) * 512 + d0 + row_)) * 32 + pc_ * 8;\
            async16(g_, (void*)((ASP) + (r_ * 256 + wv * 64) * 8));               \
        }                                                                         \
    }

#define ISSUE_XTB(CC, XP)                                                         \
    {                                                                             \
        const uint32_t* sp_ = xpack + ((size_t)((b * 16 + (CC)) * 32 + bxi)) * 2176; \
        _Pragma("unroll")                                                         \
        for (int r_ = 0; r_ < 3; ++r_) {                                          \
            const int cb_ = r_ * 256 + wv * 64;                                   \
            if (cb_ < 544) {                                                      \
                const int c_ = r_ * 256 + tid;                                    \
                async16((const void*)(sp_ + (size_t)c_ * 4),                      \
                        (void*)((XP) + (size_t)cb_ * 4));                         \
            }                                                                     \
        }                                                                         \
    }

#define STEP(KK, XP, ASP)                                                         \
    {                                                                             \
        bf16x8 af_[8];                                                            \
        _Pragma("unroll")                                                         \
        for (int i_ = 0; i_ < 8; ++i_)                                            \
            af_[i_] = *(const bf16x8*)&(ASP)[(i_ * 16 + m16) * 32 + quad * 8];    \
        bf16x8 bfr_[2];                                                           \
        _Pragma("unroll")                                                         \
        for (int j_ = 0; j_ < 2; ++j_) {                                          \
            const int row_ = ((KK) << 7) | (ob + j_ * 16 + m16);                  \
            const int u_ = SU[row_];                                              \
            const float2 g_ = PG[row_];                                           \
            const uint32_t* Xr0_ = &(XP)[u_ * 16];                                \
            const uint32_t* Xr1_ = Xr0_ + 16;                                     \
            const int s0_ = u_ & 7, s1_ = (u_ + 1) & 7;                           \
            const uint2 a0_ = *(const uint2*)&Xr0_[((q2     ^ s0_) << 1)];        \
            const uint2 a1_ = *(const uint2*)&Xr0_[(((q2+1) ^ s0_) << 1)];        \
            const uint2 c0_ = *(const uint2*)&Xr1_[((q2     ^ s1_) << 1)];        \
            const uint2 c1_ = *(const uint2*)&Xr1_[(((q2+1) ^ s1_) << 1)];        \
            uint4 rr_;                                                            \
            rr_.x = interp1(a0_.x, c0_.x, g_.x, g_.y);                            \
            rr_.y = interp1(a0_.y, c0_.y, g_.x, g_.y);                            \
            rr_.z = interp1(a1_.x, c1_.x, g_.x, g_.y);                            \
            rr_.w = interp1(a1_.y, c1_.y, g_.x, g_.y);                            \
            __builtin_memcpy(&bfr_[j_], &rr_, 16);                                \
        }                                                                         \
        _Pragma("unroll")                                                         \
        for (int i_ = 0; i_ < 8; ++i_) {                                          \
            _Pragma("unroll")                                                     \
            for (int j_ = 0; j_ < 2; ++j_)                                        \
                acc[i_][j_] = __builtin_amdgcn_mfma_f32_16x16x32_bf16(af_[i_], bfr_[j_], acc[i_][j_], 0, 0, 0); \
        }                                                                         \
    }

// 14 steps (2 cc) with slot pointers A0_..A3_; CCB is even -> first 7 steps read XTB0,
// last 7 read XTB1. Prefetch distance = 2 steps for every DMA; barrier every 2 steps.
#define HALF(CCB, A0_, A1_, A2_, A3_)                                             \
    ISSUE_A(2, (CCB), A2_); ISSUE_A(3, (CCB), A3_); ISSUE_XTB((CCB) + 1, XTB1);   \
    STEP(0, XTB0, A0_); STEP(1, XTB0, A1_); __syncthreads();                      \
    ISSUE_A(4, (CCB), A0_); ISSUE_A(5, (CCB), A1_);                               \
    STEP(2, XTB0, A2_); STEP(3, XTB0, A3_); __syncthreads();                      \
    ISSUE_A(6, (CCB), A2_); ISSUE_A(0, (CCB) + 1, A3_);                           \
    STEP(4, XTB0, A0_); STEP(5, XTB0, A1_); __syncthreads();                      \
    ISSUE_A(1, (CCB) + 1, A0_); ISSUE_A(2, (CCB) + 1, A1_);                       \
    STEP(6, XTB0, A2_); STEP(0, XTB1, A3_); __syncthreads();                      \
    ISSUE_A(3, (CCB) + 1, A2_); ISSUE_A(4, (CCB) + 1, A3_);                       \
    if ((CCB) + 2 < 16) { ISSUE_XTB((CCB) + 2, XTB0); }                           \
    STEP(1, XTB1, A0_); STEP(2, XTB1, A1_); __syncthreads();                      \
    ISSUE_A(5, (CCB) + 1, A0_); ISSUE_A(6, (CCB) + 1, A1_);                       \
    STEP(3, XTB1, A2_); STEP(4, XTB1, A3_); __syncthreads();                      \
    if ((CCB) + 2 < 16) { ISSUE_A(0, (CCB) + 2, A2_); ISSUE_A(1, (CCB) + 2, A3_); } \
    STEP(5, XTB1, A0_); STEP(6, XTB1, A1_); __syncthreads();

    f32x4 acc[8][2];
    #pragma unroll
    for (int i = 0; i < 8; ++i) {
        #pragma unroll
        for (int j = 0; j < 2; ++j) acc[i][j] = (f32x4){0.f, 0.f, 0.f, 0.f};
    }

    // ---- prologue: kick DMAs, then compute interp params (hides DMA latency) ----
    ISSUE_XTB(0, XTB0);
    ISSUE_A(0, 0, As0);
    ISSUE_A(1, 0, As1);
    for (int e = tid; e < 896; e += 256) {
        const int k  = e >> 7;
        const int ol = e & 127;
        int o = o0 + ol; if (o > OUT_LEN - 1) o = OUT_LEN - 1;
        const float t0  = (float)o;
        const float off = offs[((size_t)b * OUT_LEN + o) * K_ + k];
        float T = t0 + (float)k + off;
        T = fmaxf(T, t0);
        T = fminf(T, t0 + 6.0f);
        int u0 = (int)floorf(T);
        if (u0 > L_ - 2) u0 = L_ - 2;
        const float g0 = fmaxf(1.0f - fabsf((float)u0 - T), 0.0f);
        const float g1 = fmaxf(1.0f - fabsf((float)(u0 + 1) - T), 0.0f);
        SU[e] = u0 - o0;
        PG[e] = make_float2(g0, g1);
    }
    __syncthreads();   // drains vmcnt: XTB(0), A(0), A(1) ready; params visible

    #pragma unroll 1
    for (int s4 = 0; s4 < 16; s4 += 4) {
        HALF(s4,     As0, As1, As2, As3)
        HALF(s4 + 2, As2, As3, As0, As1)
    }

    // ---- epilogue (verified C/D layout: col=o (m16), row=quad*4+r) ----
    #pragma unroll
    for (int i = 0; i < 8; ++i) {
        const int dd = d0 + i * 16 + quad * 4;
        float bv[4];
        #pragma unroll
        for (int r = 0; r < 4; ++r) bv[r] = bias[dd + r];
        #pragma unroll
        for (int j = 0; j < 2; ++j) {
            const int oo = o0 + ob + j * 16 + m16;
            if (oo < OUT_LEN) {
                float* op = out + (size_t)b * COUT * OUT_LEN + (size_t)dd * OUT_LEN + oo;
                #pragma unroll
                for (int r = 0; r < 4; ++r)
                    op[(size_t)r * OUT_LEN] = acc[i][j][r] + bv[r];
            }
        }
    }
#undef ISSUE_A
#undef ISSUE_XTB
#undef STEP
#undef HALF
}

// ---------------- fallback (round-1 fp32 kernel, used only if ws too small) ----------------
#define BM 64
#define BN 64
#define BC 8
#define TT (BC * K_)

__global__ __launch_bounds__(256, 2)
void deform_conv1d_fallback(const float* __restrict__ x, const float* __restrict__ offsets,
                            const float* __restrict__ weight, const float* __restrict__ bias,
                            float* __restrict__ out) {
    const int o0 = blockIdx.x * BN, d0 = blockIdx.y * BM, b = blockIdx.z, tid = threadIdx.x;
    __shared__ int   SU[BN * K_];
    __shared__ float SG0[BN * K_], SG1[BN * K_];
    __shared__ float XT[BC][BN + 8];
    __shared__ float S[BC][K_][BN];
    __shared__ float WT[BM][TT + 1];
    for (int e = tid; e < BN * K_; e += 256) {
        const int ol = e / K_, k = e % K_, o = o0 + ol;
        int u0rel = 0; float g0 = 0.f, g1 = 0.f;
        if (o < OUT_LEN) {
            const float t0 = (float)o;
            const float off = offsets[(size_t)b * OUT_LEN * K_ + (size_t)o * K_ + k];
            float T = fminf(fmaxf(t0 + (float)k + off, t0), t0 + 6.0f);
            int u0 = (int)floorf(T); if (u0 > L_ - 2) u0 = L_ - 2;
            g0 = fmaxf(1.0f - fabsf((float)u0 - T), 0.0f);
            g1 = fmaxf(1.0f - fabsf((float)(u0 + 1) - T), 0.0f);
            u0rel = u0 - o0;
        }
        SU[e] = u0rel; SG0[e] = g0; SG1[e] = g1;
    }
    float acc[4][4];
    #pragma unroll
    for (int i = 0; i < 4; ++i) {
        #pragma unroll
        for (int j = 0; j < 4; ++j) acc[i][j] = 0.f;
    }
    const int ty = tid >> 4, tx = tid & 15;
    const float* xb = x + (size_t)b * CIN * L_;
    for (int c0 = 0; c0 < CIN; c0 += BC) {
        __syncthreads();
        for (int e = tid; e < BC * (BN + 7); e += 256) {
            const int cl = e / (BN + 7), j = e % (BN + 7), pos = o0 + j;
            XT[cl][j] = (pos < L_) ? xb[(size_t)(c0 + cl) * L_ + pos] : 0.f;
        }
        for (int e = tid; e < BM * TT; e += 256) {
            const int d = e / TT, t = e % TT;
            WT[d][t] = weight[(size_t)(d0 + d) * (CIN * K_) + c0 * K_ + t];
        }
        __syncthreads();
        for (int e = tid; e < BC * K_ * BN; e += 256) {
            const int cl = e / (K_ * BN), r = e % (K_ * BN), k = r / BN, ol = r % BN;
            const int p = ol * K_ + k, u = SU[p];
            S[cl][k][ol] = SG0[p] * XT[cl][u] + SG1[p] * XT[cl][u + 1];
        }
        __syncthreads();
        #pragma unroll
        for (int t = 0; t < TT; ++t) {
            const int cl = t / K_, k = t % K_;
            const float4 s4 = *(const float4*)&S[cl][k][tx * 4];
            const float w0 = WT[ty * 4 + 0][t], w1 = WT[ty * 4 + 1][t];
            const float w2 = WT[ty * 4 + 2][t], w3 = WT[ty * 4 + 3][t];
            acc[0][0] += w0 * s4.x; acc[0][1] += w0 * s4.y; acc[0][2] += w0 * s4.z; acc[0][3] += w0 * s4.w;
            acc[1][0] += w1 * s4.x; acc[1][1] += w1 * s4.y; acc[1][2] += w1 * s4.z; acc[1][3] += w1 * s4.w;
            acc[2][0] += w2 * s4.x; acc[2][1] += w2 * s4.y; acc[2][2] += w2 * s4.z; acc[2][3] += w2 * s4.w;
            acc[3][0] += w3 * s4.x; acc[3][1] += w3 * s4.y; acc[3][2] += w3 * s4.z; acc[3][3] += w3 * s4.w;
        }
    }
    #pragma unroll
    for (int i = 0; i < 4; ++i) {
        const int d = d0 + ty * 4 + i;
        const float bvv = bias[d];
        #pragma unroll
        for (int j = 0; j < 4; ++j) {
            const int o = o0 + tx * 4 + j;
            if (o < OUT_LEN)
                out[(size_t)b * COUT * OUT_LEN + (size_t)d * OUT_LEN + o] = acc[i][j] + bvv;
        }
    }
}

extern "C" void kernel_launch(void* const* d_in, const int* in_sizes, int n_in,
                              void* d_out, int out_size, void* d_ws, size_t ws_size,
                              hipStream_t stream) {
    const float* x       = (const float*)d_in[0];
    const float* offsets = (const float*)d_in[1];
    const float* weight  = (const float*)d_in[2];
    const float* bias    = (const float*)d_in[3];
    float* out = (float*)d_out;

    const size_t WR_BYTES = (size_t)512 * 512 * 7 * 2;                 // 3,670,016
    const size_t XP_BYTES = (size_t)2048 * 544 * 16 + 512;             // 17,826,304

    if (ws_size < WR_BYTES + XP_BYTES) {
        dim3 grid((OUT_LEN + BN - 1) / BN, COUT / BM, B_);
        deform_conv1d_fallback<<<grid, 256, 0, stream>>>(x, offsets, weight, bias, out);
        return;
    }

    uint32_t* Wr_u32 = (uint32_t*)d_ws;
    ushort_t* Wr     = (ushort_t*)d_ws;
    uint32_t* xpack  = (uint32_t*)((char*)d_ws + WR_BYTES);

    reorder_w_kernel<<<512, 256, 0, stream>>>(weight, Wr_u32);
    prepack_kernel<<<dim3(32, 16, B_), 256, 0, stream>>>(x, xpack);
    fused_kernel<<<dim3(32, 4, B_), 256, 0, stream>>>(offsets, Wr, xpack, bias, out);
}